// Round 6
// baseline (224.206 us; speedup 1.0000x reference)
//
#include <hip/hip_runtime.h>

using short8 = __attribute__((ext_vector_type(8))) short;
using f32x4  = __attribute__((ext_vector_type(4))) float;

#define HW   4800
#define MT   75            // 75 m-tiles of 64 (75*64 == 4800 exactly)
#define NPTS 1024
#define CDIM 256
#define NB   4
#define NROWS (NB*NPTS)    // 4096

// ---- workspace layout (bytes), total ~19.5 MiB ----
#define OFF_BITS 0
#define SZ_BITS  (NROWS*MT*8)            // u64 exclusion bitmask per (b,n)
#define OFF_PART (OFF_BITS + SZ_BITS)
#define SZ_PART  (NROWS*MT*4*4)          // per (b,n,mt): bottom-4 f32  (row-major n, mt inner)
#define OFF_AG   (OFF_PART + SZ_PART)
#define SZ_AG    (NB*MT*16384*2)         // fragment-ordered RAW bf16 A-tiles
#define OFF_KDN  (OFF_AG + SZ_AG)
#define SZ_KDN   (NROWS*CDIM*2)          // RAW bf16 kdesc
#define OFF_POS  (OFF_KDN + SZ_KDN)
#define SZ_POS   (NROWS*4)
#define OFF_INVK (OFF_POS + SZ_POS)
#define SZ_INVK  (NROWS*4)
#define OFF_NRM  (OFF_INVK + SZ_INVK)
#define SZ_NRM   (NB*HW*4)               // f32 desc2 row ssq (atomic-accumulated)
#define WS_TOTAL (OFF_NRM + SZ_NRM)

__device__ inline unsigned short f2b(float v){
  unsigned int x; __builtin_memcpy(&x, &v, 4);
  x = x + 0x7fffu + ((x >> 16) & 1u);   // RNE
  return (unsigned short)(x >> 16);
}
__device__ inline int iclamp(int v, int lo, int hi){ return v < lo ? lo : (v > hi ? hi : v); }

__device__ inline void ins4(float v, float& a0, float& a1, float& a2, float& a3){
  if (v < a3){
    if (v < a2){ a3 = a2;
      if (v < a1){ a2 = a1;
        if (v < a0){ a1 = a0; a0 = v; } else a1 = v;
      } else a2 = v;
    } else a3 = v;
  }
}

// merge two sorted-ascending 4-lists across lanes (xor partner), keep lowest 4
__device__ inline void merge4(float& s0, float& s1, float& s2, float& s3, int off){
  float b0=__shfl_xor(s0,off), b1=__shfl_xor(s1,off), b2=__shfl_xor(s2,off), b3=__shfl_xor(s3,off);
  float c0=fminf(s0,b3), c1=fminf(s1,b2), c2=fminf(s2,b1), c3=fminf(s3,b0);
  float d0=fminf(c0,c2), e2=fmaxf(c0,c2), d1=fminf(c1,c3), e3=fmaxf(c1,c3);
  s0=fminf(d0,d1); s1=fmaxf(d0,d1); s2=fminf(e2,e3); s3=fmaxf(e2,e3);
}

// 4 nearest grid-cell indices (regular 8px lattice, 60x80).
__device__ void nearest4(float px, float py, int* out){
  float aa = px*px + py*py;
  int ic = iclamp((int)floorf(px*0.125f - 0.5f) - 1, 0, 76);
  int jc = iclamp((int)floorf(py*0.125f - 0.5f) - 1, 0, 56);
  float v0=1e30f,v1=1e30f,v2=1e30f,v3=1e30f;
  int   i0=0,i1=0,i2=0,i3=0;
  for (int jj=jc; jj<jc+4; ++jj){
    for (int ii=ic; ii<ic+4; ++ii){
      float cx = (ii+0.5f)*8.f, cy = (jj+0.5f)*8.f;
      float q = (aa + (cx*cx + cy*cy)) - 2.f*(px*cx + py*cy);
      int m = jj*80 + ii;
      if (q < v3){
        if (q < v2){ v3=v2; i3=i2;
          if (q < v1){ v2=v1; i2=i1;
            if (q < v0){ v1=v0; i1=i0; v0=q; i0=m; } else { v1=q; i1=m; }
          } else { v2=q; i2=m; }
        } else { v3=q; i3=m; }
      }
    }
  }
  out[0]=i0; out[1]=i1; out[2]=i2; out[3]=i3;
}

// One wave per (b,n): raw bf16 kdn, invk, pos, exclusion bits.
__global__ __launch_bounds__(256) void prep_kernel(
    const float* kp1, const float* wkp1,
    const float* kdesc, const float* desc2,
    const float* homo,
    unsigned short* kdn, float* invk, float* pos, unsigned long long* bits)
{
  int wid  = blockIdx.x*4 + (threadIdx.x >> 6);
  int lane = threadIdx.x & 63;
  int b = wid >> 10;
  const float* kr = kdesc + (size_t)wid*CDIM + lane*4;
  float k0=kr[0], k1=kr[1], k2=kr[2], k3=kr[3];
  float ss = k0*k0 + k1*k1 + k2*k2 + k3*k3;
  for (int off=32; off>0; off>>=1) ss += __shfl_xor(ss, off);
  float ivk = 1.0f/sqrtf(ss + 1e-8f);
  {
    unsigned short* kw = kdn + (size_t)wid*CDIM + lane*4;
    kw[0]=f2b(k0); kw[1]=f2b(k1); kw[2]=f2b(k2); kw[3]=f2b(k3);
  }

  // bilinear sample at w_kp1/8 - 0.5
  float px = wkp1[(size_t)wid*2+0]*0.125f - 0.5f;
  float py = wkp1[(size_t)wid*2+1]*0.125f - 0.5f;
  float x0f = floorf(px), y0f = floorf(py);
  float wx = px - x0f, wy = py - y0f;
  int x0 = iclamp((int)x0f, 0, 79);
  int x1 = x0+1 > 79 ? 79 : x0+1;
  int y0 = iclamp((int)y0f, 0, 59);
  int y1 = y0+1 > 59 ? 59 : y0+1;
  const float* dp = desc2 + (size_t)b*CDIM*HW;
  float wss = 0.f, wdot = 0.f;
  int cbase = lane*4;
  #pragma unroll
  for (int j=0; j<4; ++j){
    const float* p = dp + (size_t)(cbase+j)*HW;
    float d00=p[y0*80+x0], d01=p[y0*80+x1];
    float d10=p[y1*80+x0], d11=p[y1*80+x1];
    float top = d00*(1.f-wx) + d01*wx;
    float bot = d10*(1.f-wx) + d11*wx;
    float wv  = top*(1.f-wy) + bot*wy;
    wss += wv*wv;
    float kvj = (j==0) ? k0 : (j==1) ? k1 : (j==2) ? k2 : k3;
    wdot += wv*kvj;
  }
  for (int off=32; off>0; off>>=1){ wss += __shfl_xor(wss, off); wdot += __shfl_xor(wdot, off); }

  if (lane == 0){
    invk[wid] = ivk;
    float invw = 1.0f/sqrtf(wss + 1e-8f);
    pos[wid] = 2.f - 2.f*(wdot*ivk*invw);

    float qx = kp1[(size_t)wid*2+0], qy = kp1[(size_t)wid*2+1];
    int c1[4]; nearest4(qx, qy, c1);
    float h[9];
    #pragma unroll
    for (int k=0; k<9; ++k) h[k] = homo[b*9 + k];
    unsigned long long* brow = bits + (size_t)wid*MT;
    for (int t=0; t<4; ++t){
      int m = c1[t]; int ii = m % 80, jj = m / 80;
      float cx = (ii+0.5f)*8.f, cy = (jj+0.5f)*8.f;
      float wz  = h[6]*cx + h[7]*cy + h[8];
      float wxp = (h[0]*cx + h[1]*cy + h[2]) / (wz + 1e-8f);
      float wyp = (h[3]*cx + h[4]*cy + h[5]) / (wz + 1e-8f);
      int c2[4]; nearest4(wxp, wyp, c2);
      for (int u=0; u<4; ++u){
        int m2 = c2[u];
        brow[m2 >> 6] |= (1ull << (m2 & 63));
      }
    }
  }
}

// Pure transpose+pack, no norm dependency: block = (mt, cq, b), 1200 blocks.
// Each thread: 16 coalesced f32 loads -> 2 short8 frag stores + partial ssq atomic.
__global__ __launch_bounds__(256) void d2t_kernel(const float* desc2, unsigned short* a_glob, float* nrm){
  int mt = blockIdx.x, cq = blockIdx.y, b = blockIdx.z;
  int t = threadIdx.x;
  int m_l = t & 63, og = t >> 6;          // og: 16-channel group within this 64-c quarter
  const float* src = desc2 + (size_t)b*CDIM*HW + (size_t)mt*64 + m_l;
  unsigned short* dst = a_glob + (size_t)(b*MT + mt)*16384;
  int msub = m_l >> 4, nl = m_l & 15;
  __shared__ float red[4][64];
  float ssq = 0.f;
  #pragma unroll
  for (int o=0; o<2; ++o){
    int c0 = cq*64 + og*16 + o*8;
    short8 pk;
    #pragma unroll
    for (int j=0; j<8; ++j){
      float f = src[(size_t)(c0+j)*HW];
      ssq += f*f;
      pk[j] = (short)f2b(f);
    }
    int kf = c0 >> 5, qd = (c0 >> 3) & 3;
    *(short8*)(dst + (((msub*8 + kf)*64 + qd*16 + nl) << 3)) = pk;
  }
  red[og][m_l] = ssq;
  __syncthreads();
  if (t < 64) atomicAdd(nrm + (size_t)b*HW + mt*64 + t,
                        red[0][t]+red[1][t]+red[2][t]+red[3][t]);
}

// GEMM+select: block = (b, mt, nh of 128 n). A staged in LDS (32 KB), B in regs
// (2 n-tiles/wave -> 64 VGPR forced live), normalization in epilogue.
__global__ __launch_bounds__(256) void gemm_select(
    const unsigned short* kdn, const unsigned short* a_glob,
    const unsigned long long* bits, const float* invk, const float* nrm,
    float* part)
{
  int idx = blockIdx.x;
  int nh  = idx / 300;
  int rem = idx - nh*300;
  int b   = rem / MT;
  int mt  = rem - b*MT;
  int t = threadIdx.x;
  int wave = t >> 6, lane = t & 63;
  int quad = lane >> 4, nl = lane & 15;

  __shared__ __align__(16) unsigned short ashare[16384];  // 32 KB fragment-ordered
  __shared__ float snrm[64];

  // B fragments + per-row scalars first (independent of LDS, overlap with staging)
  int nP = nh*128 + wave*32 + nl;          // n-tile P
  int nQ = nP + 16;                        // n-tile Q
  int rP = b*NPTS + nP, rQ = b*NPTS + nQ;
  const unsigned short* kbP = kdn + (size_t)rP*CDIM + quad*8;
  const unsigned short* kbQ = kdn + (size_t)rQ*CDIM + quad*8;
  short8 bfP[8], bfQ[8];
  #pragma unroll
  for (int kf=0; kf<8; ++kf){
    bfP[kf] = *(const short8*)(kbP + kf*32);
    bfQ[kf] = *(const short8*)(kbQ + kf*32);
  }
  float ivkP = invk[rP], ivkQ = invk[rQ];
  unsigned long long wP = bits[(size_t)rP*MT + mt];
  unsigned long long wQ = bits[(size_t)rQ*MT + mt];

  // stage A tile: 8 x (coalesced 16B load -> ds_write_b128)
  {
    const unsigned short* ag = a_glob + (size_t)(b*MT + mt)*16384;
    short8 tmp[8];
    #pragma unroll
    for (int i=0; i<8; ++i) tmp[i] = *(const short8*)(ag + ((i*256 + t) << 3));
    #pragma unroll
    for (int i=0; i<8; ++i) *(short8*)(ashare + ((i*256 + t) << 3)) = tmp[i];
    if (t < 64) snrm[t] = rsqrtf(nrm[(size_t)b*HW + mt*64 + t] + 1e-8f);
  }
  __syncthreads();

  float p0=1e30f,p1=1e30f,p2=1e30f,p3=1e30f;
  float q0=1e30f,q1=1e30f,q2=1e30f,q3=1e30f;
  #pragma unroll
  for (int msub=0; msub<4; ++msub){
    f32x4 accP = {0.f,0.f,0.f,0.f}, accQ = {0.f,0.f,0.f,0.f};
    #pragma unroll
    for (int kf=0; kf<8; ++kf){
      short8 a = *(short8*)(ashare + (((msub*8 + kf)*64 + lane) << 3));
      accP = __builtin_amdgcn_mfma_f32_16x16x32_bf16(a, bfP[kf], accP, 0, 0, 0);
      accQ = __builtin_amdgcn_mfma_f32_16x16x32_bf16(a, bfQ[kf], accQ, 0, 0, 0);
    }
    #pragma unroll
    for (int rr=0; rr<4; ++rr){
      int ml2 = msub*16 + quad*4 + rr;   // C/D: col=lane&15 (=n), row=quad*4+rr
      float sn = snrm[ml2];              // LDS broadcast (uniform per quad)
      float vP = 2.f - 2.f*accP[rr]*sn*ivkP;
      float vQ = 2.f - 2.f*accQ[rr]*sn*ivkQ;
      if (!((wP >> ml2) & 1ull)) ins4(vP, p0,p1,p2,p3);
      if (!((wQ >> ml2) & 1ull)) ins4(vQ, q0,q1,q2,q3);
    }
  }
  merge4(p0,p1,p2,p3,16); merge4(p0,p1,p2,p3,32);
  merge4(q0,q1,q2,q3,16); merge4(q0,q1,q2,q3,32);
  if (lane < 16){
    *(f32x4*)(part + ((size_t)rP*MT + mt)*4) = (f32x4){p0,p1,p2,p3};
    *(f32x4*)(part + ((size_t)rQ*MT + mt)*4) = (f32x4){q0,q1,q2,q3};
  }
}

// One wave per (b,n): coalesced read of 75 bottom-4 lists, reduce, hinge, atomic.
__global__ __launch_bounds__(1024) void finalize(const float* part, const float* pos, float* out){
  int wave = threadIdx.x >> 6, lane = threadIdx.x & 63;
  int row = blockIdx.x*16 + wave;
  const float* base = part + (size_t)row*MT*4;
  float a0=1e30f, a1=1e30f, a2=1e30f, a3=1e30f;
  {
    const f32x4 v = *(const f32x4*)(base + lane*4);      // mt = lane (coalesced 1KB)
    ins4(v[0],a0,a1,a2,a3); ins4(v[1],a0,a1,a2,a3);
    ins4(v[2],a0,a1,a2,a3); ins4(v[3],a0,a1,a2,a3);
  }
  if (lane < MT-64){
    const f32x4 v = *(const f32x4*)(base + (64+lane)*4); // mt = 64+lane
    ins4(v[0],a0,a1,a2,a3); ins4(v[1],a0,a1,a2,a3);
    ins4(v[2],a0,a1,a2,a3); ins4(v[3],a0,a1,a2,a3);
  }
  #pragma unroll
  for (int off=1; off<64; off<<=1) merge4(a0,a1,a2,a3,off);

  __shared__ float ls[16];
  if (lane == 0){
    float p = pos[row];
    ls[wave] = fmaxf(p-a0+1.f,0.f) + fmaxf(p-a1+1.f,0.f)
             + fmaxf(p-a2+1.f,0.f) + fmaxf(p-a3+1.f,0.f);
  }
  __syncthreads();
  if (threadIdx.x == 0){
    float s = 0.f;
    #pragma unroll
    for (int i=0; i<16; ++i) s += ls[i];
    atomicAdd(out, s * (1.0f/16384.0f));
  }
}

__global__ void ws_too_small(float* out){ out[0] = -12345.0f; }

extern "C" void kernel_launch(void* const* d_in, const int* in_sizes, int n_in,
                              void* d_out, int out_size, void* d_ws, size_t ws_size,
                              hipStream_t stream) {
  (void)in_sizes; (void)n_in; (void)out_size;
  if (ws_size < (size_t)WS_TOTAL){
    ws_too_small<<<1, 1, 0, stream>>>((float*)d_out);
    return;
  }
  const float* kp1   = (const float*)d_in[0];
  const float* wkp1  = (const float*)d_in[1];
  const float* kdesc = (const float*)d_in[2];
  const float* desc2 = (const float*)d_in[3];
  const float* homo  = (const float*)d_in[4];

  char* ws = (char*)d_ws;
  unsigned long long* bits = (unsigned long long*)(ws + OFF_BITS);
  float*          part   = (float*)(ws + OFF_PART);
  unsigned short* a_glob = (unsigned short*)(ws + OFF_AG);
  unsigned short* kdn    = (unsigned short*)(ws + OFF_KDN);
  float*          pos    = (float*)(ws + OFF_POS);
  float*          invk   = (float*)(ws + OFF_INVK);
  float*          nrm    = (float*)(ws + OFF_NRM);

  hipMemsetAsync(bits, 0, SZ_BITS, stream);
  hipMemsetAsync(nrm, 0, SZ_NRM, stream);
  hipMemsetAsync(d_out, 0, 4, stream);

  prep_kernel<<<1024, 256, 0, stream>>>(kp1, wkp1, kdesc, desc2, homo, kdn, invk, pos, bits);
  d2t_kernel<<<dim3(MT, 4, NB), 256, 0, stream>>>(desc2, a_glob, nrm);
  gemm_select<<<2400, 256, 0, stream>>>(kdn, a_glob, bits, invk, nrm, part);
  finalize<<<256, 1024, 0, stream>>>(part, pos, (float*)d_out);
}

// Round 7
// 218.654 us; speedup vs baseline: 1.0254x; 1.0254x over previous
//
#include <hip/hip_runtime.h>

using short8 = __attribute__((ext_vector_type(8))) short;
using f32x4  = __attribute__((ext_vector_type(4))) float;

#define HW   4800
#define MT   75            // 75 m-tiles of 64 (75*64 == 4800 exactly)
#define NPTS 1024
#define CDIM 256
#define NB   4
#define NROWS (NB*NPTS)    // 4096

// ---- workspace layout (bytes), total ~19.5 MiB ----
#define OFF_BITS 0
#define SZ_BITS  (NROWS*MT*8)            // u64 exclusion bitmask per (b,n)
#define OFF_PART (OFF_BITS + SZ_BITS)
#define SZ_PART  (NROWS*MT*4*4)          // per (b,mt,n): bottom-4 f32 (n inner)
#define OFF_AG   (OFF_PART + SZ_PART)
#define SZ_AG    (NB*MT*16384*2)         // fragment-ordered RAW bf16 A-tiles
#define OFF_KDN  (OFF_AG + SZ_AG)
#define SZ_KDN   (NROWS*CDIM*2)          // RAW bf16 kdesc
#define OFF_POS  (OFF_KDN + SZ_KDN)
#define SZ_POS   (NROWS*4)
#define OFF_INVK (OFF_POS + SZ_POS)
#define SZ_INVK  (NROWS*4)
#define OFF_NRM  (OFF_INVK + SZ_INVK)
#define SZ_NRM   (NB*HW*4)               // f32 desc2 row ssq (atomic-accumulated)
#define WS_TOTAL (OFF_NRM + SZ_NRM)

__device__ inline unsigned short f2b(float v){
  unsigned int x; __builtin_memcpy(&x, &v, 4);
  x = x + 0x7fffu + ((x >> 16) & 1u);   // RNE
  return (unsigned short)(x >> 16);
}
__device__ inline int iclamp(int v, int lo, int hi){ return v < lo ? lo : (v > hi ? hi : v); }

__device__ inline void ins4(float v, float& a0, float& a1, float& a2, float& a3){
  if (v < a3){
    if (v < a2){ a3 = a2;
      if (v < a1){ a2 = a1;
        if (v < a0){ a1 = a0; a0 = v; } else a1 = v;
      } else a2 = v;
    } else a3 = v;
  }
}

// merge two sorted-ascending 4-lists across lanes (xor partner), keep lowest 4
__device__ inline void merge4(float& s0, float& s1, float& s2, float& s3, int off){
  float b0=__shfl_xor(s0,off), b1=__shfl_xor(s1,off), b2=__shfl_xor(s2,off), b3=__shfl_xor(s3,off);
  float c0=fminf(s0,b3), c1=fminf(s1,b2), c2=fminf(s2,b1), c3=fminf(s3,b0);
  float d0=fminf(c0,c2), e2=fmaxf(c0,c2), d1=fminf(c1,c3), e3=fmaxf(c1,c3);
  s0=fminf(d0,d1); s1=fmaxf(d0,d1); s2=fminf(e2,e3); s3=fmaxf(e2,e3);
}

// 4 nearest grid-cell indices (regular 8px lattice, 60x80).
__device__ void nearest4(float px, float py, int* out){
  float aa = px*px + py*py;
  int ic = iclamp((int)floorf(px*0.125f - 0.5f) - 1, 0, 76);
  int jc = iclamp((int)floorf(py*0.125f - 0.5f) - 1, 0, 56);
  float v0=1e30f,v1=1e30f,v2=1e30f,v3=1e30f;
  int   i0=0,i1=0,i2=0,i3=0;
  for (int jj=jc; jj<jc+4; ++jj){
    for (int ii=ic; ii<ic+4; ++ii){
      float cx = (ii+0.5f)*8.f, cy = (jj+0.5f)*8.f;
      float q = (aa + (cx*cx + cy*cy)) - 2.f*(px*cx + py*cy);
      int m = jj*80 + ii;
      if (q < v3){
        if (q < v2){ v3=v2; i3=i2;
          if (q < v1){ v2=v1; i2=i1;
            if (q < v0){ v1=v0; i1=i0; v0=q; i0=m; } else { v1=q; i1=m; }
          } else { v2=q; i2=m; }
        } else { v3=q; i3=m; }
      }
    }
  }
  out[0]=i0; out[1]=i1; out[2]=i2; out[3]=i3;
}

// One wave per (b,n): raw bf16 kdn, invk, pos, exclusion bits.
__global__ __launch_bounds__(256) void prep_kernel(
    const float* kp1, const float* wkp1,
    const float* kdesc, const float* desc2,
    const float* homo,
    unsigned short* kdn, float* invk, float* pos, unsigned long long* bits)
{
  int wid  = blockIdx.x*4 + (threadIdx.x >> 6);
  int lane = threadIdx.x & 63;
  int b = wid >> 10;
  const float* kr = kdesc + (size_t)wid*CDIM + lane*4;
  float k0=kr[0], k1=kr[1], k2=kr[2], k3=kr[3];
  float ss = k0*k0 + k1*k1 + k2*k2 + k3*k3;
  for (int off=32; off>0; off>>=1) ss += __shfl_xor(ss, off);
  float ivk = 1.0f/sqrtf(ss + 1e-8f);
  {
    unsigned short* kw = kdn + (size_t)wid*CDIM + lane*4;
    kw[0]=f2b(k0); kw[1]=f2b(k1); kw[2]=f2b(k2); kw[3]=f2b(k3);
  }

  // bilinear sample at w_kp1/8 - 0.5
  float px = wkp1[(size_t)wid*2+0]*0.125f - 0.5f;
  float py = wkp1[(size_t)wid*2+1]*0.125f - 0.5f;
  float x0f = floorf(px), y0f = floorf(py);
  float wx = px - x0f, wy = py - y0f;
  int x0 = iclamp((int)x0f, 0, 79);
  int x1 = x0+1 > 79 ? 79 : x0+1;
  int y0 = iclamp((int)y0f, 0, 59);
  int y1 = y0+1 > 59 ? 59 : y0+1;
  const float* dp = desc2 + (size_t)b*CDIM*HW;
  float wss = 0.f, wdot = 0.f;
  int cbase = lane*4;
  #pragma unroll
  for (int j=0; j<4; ++j){
    const float* p = dp + (size_t)(cbase+j)*HW;
    float d00=p[y0*80+x0], d01=p[y0*80+x1];
    float d10=p[y1*80+x0], d11=p[y1*80+x1];
    float top = d00*(1.f-wx) + d01*wx;
    float bot = d10*(1.f-wx) + d11*wx;
    float wv  = top*(1.f-wy) + bot*wy;
    wss += wv*wv;
    float kvj = (j==0) ? k0 : (j==1) ? k1 : (j==2) ? k2 : k3;
    wdot += wv*kvj;
  }
  for (int off=32; off>0; off>>=1){ wss += __shfl_xor(wss, off); wdot += __shfl_xor(wdot, off); }

  if (lane == 0){
    invk[wid] = ivk;
    float invw = 1.0f/sqrtf(wss + 1e-8f);
    pos[wid] = 2.f - 2.f*(wdot*ivk*invw);

    float qx = kp1[(size_t)wid*2+0], qy = kp1[(size_t)wid*2+1];
    int c1[4]; nearest4(qx, qy, c1);
    float h[9];
    #pragma unroll
    for (int k=0; k<9; ++k) h[k] = homo[b*9 + k];
    unsigned long long* brow = bits + (size_t)wid*MT;
    for (int t=0; t<4; ++t){
      int m = c1[t]; int ii = m % 80, jj = m / 80;
      float cx = (ii+0.5f)*8.f, cy = (jj+0.5f)*8.f;
      float wz  = h[6]*cx + h[7]*cy + h[8];
      float wxp = (h[0]*cx + h[1]*cy + h[2]) / (wz + 1e-8f);
      float wyp = (h[3]*cx + h[4]*cy + h[5]) / (wz + 1e-8f);
      int c2[4]; nearest4(wxp, wyp, c2);
      for (int u=0; u<4; ++u){
        int m2 = c2[u];
        brow[m2 >> 6] |= (1ull << (m2 & 63));
      }
    }
  }
}

// Pure transpose+pack: block = (mt, cq, b), 1200 blocks.
__global__ __launch_bounds__(256) void d2t_kernel(const float* desc2, unsigned short* a_glob, float* nrm){
  int mt = blockIdx.x, cq = blockIdx.y, b = blockIdx.z;
  int t = threadIdx.x;
  int m_l = t & 63, og = t >> 6;          // og: 16-channel group within this 64-c quarter
  const float* src = desc2 + (size_t)b*CDIM*HW + (size_t)mt*64 + m_l;
  unsigned short* dst = a_glob + (size_t)(b*MT + mt)*16384;
  int msub = m_l >> 4, nl = m_l & 15;
  __shared__ float red[4][64];
  float ssq = 0.f;
  #pragma unroll
  for (int o=0; o<2; ++o){
    int c0 = cq*64 + og*16 + o*8;
    short8 pk;
    #pragma unroll
    for (int j=0; j<8; ++j){
      float f = src[(size_t)(c0+j)*HW];
      ssq += f*f;
      pk[j] = (short)f2b(f);
    }
    int kf = c0 >> 5, qd = (c0 >> 3) & 3;
    *(short8*)(dst + (((msub*8 + kf)*64 + qd*16 + nl) << 3)) = pk;
  }
  red[og][m_l] = ssq;
  __syncthreads();
  if (t < 64) atomicAdd(nrm + (size_t)b*HW + mt*64 + t,
                        red[0][t]+red[1][t]+red[2][t]+red[3][t]);
}

// GEMM+select: block = (b, mt, nh of 128 n). A staged in LDS (32 KB), B in regs.
// __launch_bounds__(256,2): 256-VGPR budget so bfP/bfQ stay resident (NO scratch
// spill — R6's VGPR=64 cap spilled the inner loop to HBM, the ~100us floor).
__global__ __launch_bounds__(256, 2) void gemm_select(
    const unsigned short* kdn, const unsigned short* a_glob,
    const unsigned long long* bits, const float* invk, const float* nrm,
    float* part)
{
  int idx = blockIdx.x;
  int nh  = idx / 300;
  int rem = idx - nh*300;
  int b   = rem / MT;
  int mt  = rem - b*MT;
  int t = threadIdx.x;
  int wave = t >> 6, lane = t & 63;
  int quad = lane >> 4, nl = lane & 15;

  __shared__ __align__(16) unsigned short ashare[16384];  // 32 KB fragment-ordered
  __shared__ float snrm[64];

  // B fragments + per-row scalars first (independent of LDS, overlap with staging)
  int nP = nh*128 + wave*32 + nl;          // n-tile P
  int nQ = nP + 16;                        // n-tile Q
  int rP = b*NPTS + nP, rQ = b*NPTS + nQ;
  const unsigned short* kbP = kdn + (size_t)rP*CDIM + quad*8;
  const unsigned short* kbQ = kdn + (size_t)rQ*CDIM + quad*8;
  short8 bfP[8], bfQ[8];
  #pragma unroll
  for (int kf=0; kf<8; ++kf){
    bfP[kf] = *(const short8*)(kbP + kf*32);
    bfQ[kf] = *(const short8*)(kbQ + kf*32);
  }
  float ivkP = invk[rP], ivkQ = invk[rQ];
  unsigned long long wP = bits[(size_t)rP*MT + mt];
  unsigned long long wQ = bits[(size_t)rQ*MT + mt];

  // stage A tile: 8 x (coalesced 16B load -> ds_write_b128)
  {
    const unsigned short* ag = a_glob + (size_t)(b*MT + mt)*16384;
    short8 tmp[8];
    #pragma unroll
    for (int i=0; i<8; ++i) tmp[i] = *(const short8*)(ag + ((i*256 + t) << 3));
    #pragma unroll
    for (int i=0; i<8; ++i) *(short8*)(ashare + ((i*256 + t) << 3)) = tmp[i];
    if (t < 64) snrm[t] = rsqrtf(nrm[(size_t)b*HW + mt*64 + t] + 1e-8f);
  }
  __syncthreads();

  float p0=1e30f,p1=1e30f,p2=1e30f,p3=1e30f;
  float q0=1e30f,q1=1e30f,q2=1e30f,q3=1e30f;
  #pragma unroll
  for (int msub=0; msub<4; ++msub){
    f32x4 accP = {0.f,0.f,0.f,0.f}, accQ = {0.f,0.f,0.f,0.f};
    #pragma unroll
    for (int kf=0; kf<8; ++kf){
      short8 a = *(short8*)(ashare + (((msub*8 + kf)*64 + lane) << 3));
      accP = __builtin_amdgcn_mfma_f32_16x16x32_bf16(a, bfP[kf], accP, 0, 0, 0);
      accQ = __builtin_amdgcn_mfma_f32_16x16x32_bf16(a, bfQ[kf], accQ, 0, 0, 0);
    }
    #pragma unroll
    for (int rr=0; rr<4; ++rr){
      int ml2 = msub*16 + quad*4 + rr;   // C/D: col=lane&15 (=n), row=quad*4+rr
      float sn = snrm[ml2];              // LDS broadcast (uniform per quad)
      float vP = 2.f - 2.f*accP[rr]*sn*ivkP;
      float vQ = 2.f - 2.f*accQ[rr]*sn*ivkQ;
      if (!((wP >> ml2) & 1ull)) ins4(vP, p0,p1,p2,p3);
      if (!((wQ >> ml2) & 1ull)) ins4(vQ, q0,q1,q2,q3);
    }
  }
  merge4(p0,p1,p2,p3,16); merge4(p0,p1,p2,p3,32);
  merge4(q0,q1,q2,q3,16); merge4(q0,q1,q2,q3,32);
  if (lane < 16){
    // (b,mt,n) layout: block writes contiguous full cache lines, single writer
    *(f32x4*)(part + ((size_t)(b*MT + mt)*NPTS + nP)*4) = (f32x4){p0,p1,p2,p3};
    *(f32x4*)(part + ((size_t)(b*MT + mt)*NPTS + nQ)*4) = (f32x4){q0,q1,q2,q3};
  }
}

// One wave per (b,n): reduce bottom-4 over 75 m-tiles, hinge, atomic into d_out.
__global__ __launch_bounds__(1024) void finalize(const float* part, const float* pos, float* out){
  int wave = threadIdx.x >> 6, lane = threadIdx.x & 63;
  int row = blockIdx.x*16 + wave;
  int b = row >> 10, n = row & 1023;
  float a0=1e30f, a1=1e30f, a2=1e30f, a3=1e30f;
  {
    const f32x4 v = *(const f32x4*)(part + ((size_t)(b*MT + lane)*NPTS + n)*4);
    ins4(v[0],a0,a1,a2,a3); ins4(v[1],a0,a1,a2,a3);
    ins4(v[2],a0,a1,a2,a3); ins4(v[3],a0,a1,a2,a3);
  }
  if (lane < MT-64){
    const f32x4 v = *(const f32x4*)(part + ((size_t)(b*MT + 64 + lane)*NPTS + n)*4);
    ins4(v[0],a0,a1,a2,a3); ins4(v[1],a0,a1,a2,a3);
    ins4(v[2],a0,a1,a2,a3); ins4(v[3],a0,a1,a2,a3);
  }
  #pragma unroll
  for (int off=1; off<64; off<<=1) merge4(a0,a1,a2,a3,off);

  __shared__ float ls[16];
  if (lane == 0){
    float p = pos[row];
    ls[wave] = fmaxf(p-a0+1.f,0.f) + fmaxf(p-a1+1.f,0.f)
             + fmaxf(p-a2+1.f,0.f) + fmaxf(p-a3+1.f,0.f);
  }
  __syncthreads();
  if (threadIdx.x == 0){
    float s = 0.f;
    #pragma unroll
    for (int i=0; i<16; ++i) s += ls[i];
    atomicAdd(out, s * (1.0f/16384.0f));
  }
}

__global__ void ws_too_small(float* out){ out[0] = -12345.0f; }

extern "C" void kernel_launch(void* const* d_in, const int* in_sizes, int n_in,
                              void* d_out, int out_size, void* d_ws, size_t ws_size,
                              hipStream_t stream) {
  (void)in_sizes; (void)n_in; (void)out_size;
  if (ws_size < (size_t)WS_TOTAL){
    ws_too_small<<<1, 1, 0, stream>>>((float*)d_out);
    return;
  }
  const float* kp1   = (const float*)d_in[0];
  const float* wkp1  = (const float*)d_in[1];
  const float* kdesc = (const float*)d_in[2];
  const float* desc2 = (const float*)d_in[3];
  const float* homo  = (const float*)d_in[4];

  char* ws = (char*)d_ws;
  unsigned long long* bits = (unsigned long long*)(ws + OFF_BITS);
  float*          part   = (float*)(ws + OFF_PART);
  unsigned short* a_glob = (unsigned short*)(ws + OFF_AG);
  unsigned short* kdn    = (unsigned short*)(ws + OFF_KDN);
  float*          pos    = (float*)(ws + OFF_POS);
  float*          invk   = (float*)(ws + OFF_INVK);
  float*          nrm    = (float*)(ws + OFF_NRM);

  hipMemsetAsync(bits, 0, SZ_BITS, stream);
  hipMemsetAsync(nrm, 0, SZ_NRM, stream);
  hipMemsetAsync(d_out, 0, 4, stream);

  prep_kernel<<<1024, 256, 0, stream>>>(kp1, wkp1, kdesc, desc2, homo, kdn, invk, pos, bits);
  d2t_kernel<<<dim3(MT, 4, NB), 256, 0, stream>>>(desc2, a_glob, nrm);
  gemm_select<<<2400, 256, 0, stream>>>(kdn, a_glob, bits, invk, nrm, part);
  finalize<<<256, 1024, 0, stream>>>(part, pos, (float*)d_out);
}